// Round 7
// baseline (712.263 us; speedup 1.0000x reference)
//
#include <hip/hip_runtime.h>
#include <hip/hip_bf16.h>

#define FPS_THREADS 512
#define PAIRS_PER_THR 16     // 16 float2 = 32 points per thread (16384/512)
#define CONV_BLOCKS 120
#define MEGA_BLOCKS 512

typedef __attribute__((ext_vector_type(8))) short bf16x8;
typedef __attribute__((ext_vector_type(4))) float f32x4;
typedef __attribute__((ext_vector_type(2))) float f32x2;

// ---------------------------------------------------------------------------
// helpers
// ---------------------------------------------------------------------------
__device__ inline unsigned long long shfl_down_u64(unsigned long long x, int off) {
    unsigned int lo = (unsigned int)(x & 0xFFFFFFFFull);
    unsigned int hi = (unsigned int)(x >> 32);
    lo = __shfl_down(lo, off, 64);
    hi = __shfl_down(hi, off, 64);
    return (((unsigned long long)hi) << 32) | lo;
}

__device__ inline unsigned short f2bf(float x) {
    union { float f; unsigned int u; } v; v.f = x;
    unsigned int r = v.u + 0x7FFFu + ((v.u >> 16) & 1u);   // round-to-nearest-even
    return (unsigned short)(r >> 16);
}

// rocPRIM-style 64-lane max via DPP: row_shr 1/2/4/8 + row_bcast 15/31.
__device__ inline float wave_max_dpp(float v) {
    int w = __float_as_int(v);
#define DPP_MAX_STEP(ctrl, rmask)                                             \
    {                                                                         \
        int _t = __builtin_amdgcn_update_dpp(w, w, ctrl, rmask, 0xf, false);  \
        w = __float_as_int(fmaxf(__int_as_float(w), __int_as_float(_t)));     \
    }
    DPP_MAX_STEP(0x111, 0xf)   // row_shr:1
    DPP_MAX_STEP(0x112, 0xf)   // row_shr:2
    DPP_MAX_STEP(0x114, 0xf)   // row_shr:4
    DPP_MAX_STEP(0x118, 0xf)   // row_shr:8
    DPP_MAX_STEP(0x142, 0xa)   // row_bcast:15
    DPP_MAX_STEP(0x143, 0xc)   // row_bcast:31
#undef DPP_MAX_STEP
    return __int_as_float(__builtin_amdgcn_readlane(w, 63));
}

// device-scope grid barrier over MEGA_BLOCKS co-resident blocks
__device__ __forceinline__ void grid_barrier(int* c, int target) {
    __threadfence();
    __syncthreads();
    if (threadIdx.x == 0) {
        __hip_atomic_fetch_add(c, 1, __ATOMIC_ACQ_REL, __HIP_MEMORY_SCOPE_AGENT);
        while (__hip_atomic_load(c, __ATOMIC_ACQUIRE, __HIP_MEMORY_SCOPE_AGENT) < target)
            __builtin_amdgcn_s_sleep(1);
    }
    __syncthreads();
}

// ---------------------------------------------------------------------------
// 1. FPS (blocks 0..7) + weight transpose/convert + stats/counter zeroing
//    (blocks 8..127, runs in the shadow of the serial FPS).
//    Distance update on float2 (v_pk_* dual-FP32); argmax scan ascending j
//    with strict > (first max = smallest index). Same per-point op order as
//    prior passing rounds.
// ---------------------------------------------------------------------------
__global__ __launch_bounds__(FPS_THREADS) void fps_conv_kernel(
        const float* __restrict__ src, int* __restrict__ cp_idx,
        float* __restrict__ out_cp,
        const float* __restrict__ W1, const float* __restrict__ W2,
        unsigned short* __restrict__ W1t, unsigned short* __restrict__ W2t,
        float* __restrict__ stats, int* __restrict__ ctr, int N, int K) {
    const int t = threadIdx.x;
    if (blockIdx.x >= 8) {
        const int cb = blockIdx.x - 8;
        if (cb == 0) {
            stats[t] = 0.f; stats[t + 512] = 0.f;
            stats[t + 1024] = 0.f; stats[t + 1536] = 0.f;
            if (t < 8) ctr[t] = 0;
        }
        for (size_t idx = (size_t)cb * FPS_THREADS + t; idx < (size_t)2048 * 512;
             idx += (size_t)CONV_BLOCKS * FPS_THREADS) {
            int k = (int)(idx >> 9), n = (int)(idx & 511);
            W1t[(size_t)n * 2048 + k] = f2bf(W1[idx]);
        }
        for (size_t idx = (size_t)cb * FPS_THREADS + t; idx < (size_t)512 * 512;
             idx += (size_t)CONV_BLOCKS * FPS_THREADS) {
            int k = (int)(idx >> 9), n = (int)(idx & 511);
            W2t[(size_t)n * 512 + k] = f2bf(W2[idx]);
        }
        return;
    }

    const int b = blockIdx.x;
    const float* p = src + (size_t)b * N * 3;

    f32x2 px2[PAIRS_PER_THR], py2[PAIRS_PER_THR], pz2[PAIRS_PER_THR], dm2[PAIRS_PER_THR];
#pragma unroll
    for (int a = 0; a < PAIRS_PER_THR; ++a) {
        int j0 = (2 * a) * FPS_THREADS + t;
        int j1 = (2 * a + 1) * FPS_THREADS + t;
        px2[a] = (f32x2){p[j0 * 3 + 0], p[j1 * 3 + 0]};
        py2[a] = (f32x2){p[j0 * 3 + 1], p[j1 * 3 + 1]};
        pz2[a] = (f32x2){p[j0 * 3 + 2], p[j1 * 3 + 2]};
        dm2[a] = (f32x2){__builtin_huge_valf(), __builtin_huge_valf()};
    }

    __shared__ unsigned long long slot[3];
    if (t == 0) { slot[0] = 0ull; slot[1] = 0ull; slot[2] = 0ull; }
    __syncthreads();

    int far = 0;
    int cur = 0;
    for (int k = 0;; ++k) {
        const float cx = p[far * 3 + 0];
        const float cy = p[far * 3 + 1];
        const float cz = p[far * 3 + 2];
        if (t == 0) {
            cp_idx[b * K + k] = far;
            out_cp[(b * K + k) * 3 + 0] = cx;
            out_cp[(b * K + k) * 3 + 1] = cy;
            out_cp[(b * K + k) * 3 + 2] = cz;
        }
        if (k == K - 1) break;

        const f32x2 vcx = (f32x2){cx, cx};
        const f32x2 vcy = (f32x2){cy, cy};
        const f32x2 vcz = (f32x2){cz, cz};

        // pass 1: packed dmin update (v_pk_add/v_pk_mul/v_pk_fma)
#pragma unroll
        for (int a = 0; a < PAIRS_PER_THR; ++a) {
            f32x2 dx = px2[a] - vcx;
            f32x2 dy = py2[a] - vcy;
            f32x2 dz = pz2[a] - vcz;
            f32x2 d = dx * dx;
            d += dy * dy;
            d += dz * dz;
            f32x2 dm = dm2[a];
            dm.x = fminf(dm.x, d.x);
            dm.y = fminf(dm.y, d.y);
            dm2[a] = dm;
        }
        // pass 2: per-thread argmax, ascending j, strict > (first max wins)
        float tmax = -1.0f;
        int jbest = 0;
#pragma unroll
        for (int a = 0; a < PAIRS_PER_THR; ++a) {
            f32x2 dm = dm2[a];
            bool c0 = dm.x > tmax;
            tmax = c0 ? dm.x : tmax;
            jbest = c0 ? ((2 * a) * FPS_THREADS + t) : jbest;
            bool c1 = dm.y > tmax;
            tmax = c1 ? dm.y : tmax;
            jbest = c1 ? ((2 * a + 1) * FPS_THREADS + t) : jbest;
        }

        const float wmax = wave_max_dpp(tmax);
        if (tmax == wmax) {
            unsigned long long pk =
                (((unsigned long long)__float_as_uint(wmax)) << 32) |
                (unsigned long long)(0xFFFFFFFFu - (unsigned int)jbest);
            atomicMax(&slot[cur], pk);
        }
        const int nxt = (cur == 2) ? 0 : cur + 1;
        if (t == 0) slot[nxt] = 0ull;
        __syncthreads();
        unsigned long long bb = slot[cur];
        far = (int)(0xFFFFFFFFu - (unsigned int)(bb & 0xFFFFFFFFull));
        cur = nxt;
    }
}

// ---------------------------------------------------------------------------
// gemm unit (bf16 MFMA, 64x64 tile, bias + column stats) — device function
// ---------------------------------------------------------------------------
__device__ __forceinline__ void gemm_unit(
        const unsigned short* __restrict__ A, const unsigned short* __restrict__ Bt,
        const float* __restrict__ bias, float* __restrict__ C,
        float* __restrict__ psum, float* __restrict__ psumsq,
        int N, int K, int m0, int n0,
        unsigned short (&As)[64][72], unsigned short (&Bs)[64][72],
        float (&sS)[64], float (&sSS)[64]) {
    const int tid = threadIdx.x;
    const int w = tid >> 6, l = tid & 63;

    f32x4 acc[4];
#pragma unroll
    for (int nt = 0; nt < 4; ++nt) acc[nt] = (f32x4){0.f, 0.f, 0.f, 0.f};

    const int lr = l & 15;
    const int lg = l >> 4;

    for (int kt = 0; kt < K; kt += 64) {
        __syncthreads();
#pragma unroll
        for (int s = 0; s < 2; ++s) {
            int u = tid + s * 256;
            int row = u >> 3, kc = (u & 7) * 8;
            *reinterpret_cast<uint4*>(&As[row][kc]) =
                *reinterpret_cast<const uint4*>(&A[(size_t)(m0 + row) * K + kt + kc]);
            *reinterpret_cast<uint4*>(&Bs[row][kc]) =
                *reinterpret_cast<const uint4*>(&Bt[(size_t)(n0 + row) * K + kt + kc]);
        }
        __syncthreads();
#pragma unroll
        for (int kf = 0; kf < 2; ++kf) {
            bf16x8 af = *reinterpret_cast<const bf16x8*>(&As[w * 16 + lr][kf * 32 + lg * 8]);
#pragma unroll
            for (int nt = 0; nt < 4; ++nt) {
                bf16x8 bfr = *reinterpret_cast<const bf16x8*>(&Bs[nt * 16 + lr][kf * 32 + lg * 8]);
                acc[nt] = __builtin_amdgcn_mfma_f32_16x16x32_bf16(af, bfr, acc[nt], 0, 0, 0);
            }
        }
    }

    if (tid < 64) { sS[tid] = 0.f; sSS[tid] = 0.f; }
    __syncthreads();
#pragma unroll
    for (int nt = 0; nt < 4; ++nt) {
        const int col = n0 + nt * 16 + lr;
        const float bv = bias[col];
        float s = 0.f, ss = 0.f;
#pragma unroll
        for (int r = 0; r < 4; ++r) {
            const int row = m0 + w * 16 + lg * 4 + r;
            float v = acc[nt][r] + bv;
            C[(size_t)row * N + col] = v;
            s += v; ss += v * v;
        }
        s += __shfl_xor(s, 16, 64); ss += __shfl_xor(ss, 16, 64);
        s += __shfl_xor(s, 32, 64); ss += __shfl_xor(ss, 32, 64);
        if (lg == 0) {
            atomicAdd(&sS[nt * 16 + lr], s);
            atomicAdd(&sSS[nt * 16 + lr], ss);
        }
    }
    __syncthreads();
    if (tid < 64) {
        atomicAdd(&psum[n0 + tid], sS[tid]);
        atomicAdd(&psumsq[n0 + tid], sSS[tid]);
    }
}

// ---------------------------------------------------------------------------
// 2. Mega kernel: nn+gather -> gemm1+stats -> bn1 -> gemm2+stats -> bn2+head
//    -> rbf, with device-scope barriers. 512 blocks x 256 threads
//    (2 blocks/CU co-resident -> spin barriers safe).
// ---------------------------------------------------------------------------
__global__ __launch_bounds__(256) void mega_kernel(
        const float* __restrict__ src, const float* __restrict__ tgt,
        const float* __restrict__ cp, const int* __restrict__ cp_idx,
        const float* __restrict__ src_feats, const float* __restrict__ tgt_feats,
        unsigned short* __restrict__ mlp_b,
        unsigned short* __restrict__ W1t, unsigned short* __restrict__ W2t,
        const float* __restrict__ b1, const float* __restrict__ g1, const float* __restrict__ beta1,
        const float* __restrict__ b2, const float* __restrict__ g2, const float* __restrict__ beta2,
        const float* __restrict__ W3, const float* __restrict__ b3,
        float* __restrict__ h1, unsigned short* __restrict__ h1b, float* __restrict__ h2,
        float* __restrict__ stats, int* __restrict__ ctr,
        float* __restrict__ out_w, float* __restrict__ outp, float* __restrict__ delta,
        int N, int M, int F, int Hc) {
    __shared__ __align__(16) unsigned short As[64][72];
    __shared__ __align__(16) unsigned short Bs[64][72];
    __shared__ float sS[64], sSS[64];
    __shared__ unsigned long long redu[4];
    __shared__ int snn;
    __shared__ float redh[4][3];
    __shared__ float scx[128], scy[128], scz[128], swx[128], swy[128], swz[128];

    const int blk = blockIdx.x;
    const int t = threadIdx.x;
    float* psum1 = stats;
    float* psumsq1 = stats + 512;
    float* psum2 = stats + 1024;
    float* psumsq2 = stats + 1536;
    const float invM = 1.0f / 1024.0f;

    // ---- P0: nearest-target + gather for bk = blk and blk + 512 ----
    for (int half = 0; half < 2; ++half) {
        const int bk = blk + half * 512;
        const int b = bk >> 7;
        const float* tp = tgt + (size_t)b * M * 3;
        const float cx = cp[bk * 3 + 0], cy = cp[bk * 3 + 1], cz = cp[bk * 3 + 2];
        const float cp2 = cx * cx + cy * cy + cz * cz;

        unsigned long long best = ~0ull;
#pragma unroll 4
        for (int m = t; m < M; m += 256) {
            float tx = tp[m * 3 + 0], ty = tp[m * 3 + 1], tz = tp[m * 3 + 2];
            float tg2 = tx * tx + ty * ty + tz * tz;
            float cross = cx * tx + cy * ty + cz * tz;
            float v = (cp2 + tg2) - 2.0f * cross;
            unsigned int fb = __float_as_uint(v);
            fb = (fb & 0x80000000u) ? ~fb : (fb | 0x80000000u);
            unsigned long long pk = (((unsigned long long)fb) << 32) | (unsigned int)m;
            best = (pk < best) ? pk : best;
        }
#pragma unroll
        for (int off = 32; off >= 1; off >>= 1) {
            unsigned long long o = shfl_down_u64(best, off);
            best = (o < best) ? o : best;
        }
        if ((t & 63) == 0) redu[t >> 6] = best;
        __syncthreads();
        if (t == 0) {
            unsigned long long bb = redu[0];
            for (int wv = 1; wv < 4; ++wv) bb = (redu[wv] < bb) ? redu[wv] : bb;
            snn = (int)(bb & 0xFFFFFFFFull);
        }
        __syncthreads();
        const int nn = snn;

        const float4* a4p = reinterpret_cast<const float4*>(
            src_feats + ((size_t)b * N + cp_idx[bk]) * F);
        const float4* c4p = reinterpret_cast<const float4*>(
            tgt_feats + ((size_t)b * M + nn) * F);
        unsigned short* o = mlp_b + (size_t)bk * 2 * F;
        float4 av = a4p[t];
        float4 cv = c4p[t];
        ushort4 a4, c4;
        a4.x = f2bf(av.x); a4.y = f2bf(av.y); a4.z = f2bf(av.z); a4.w = f2bf(av.w);
        c4.x = f2bf(cv.x); c4.y = f2bf(cv.y); c4.z = f2bf(cv.z); c4.w = f2bf(cv.w);
        *reinterpret_cast<ushort4*>(&o[t * 4]) = a4;
        *reinterpret_cast<ushort4*>(&o[F + t * 4]) = c4;
        __syncthreads();
    }
    grid_barrier(&ctr[0], MEGA_BLOCKS);

    // ---- P1: gemm1 (1024x512x2048) on blocks 0..127 ----
    if (blk < 128) {
        gemm_unit(mlp_b, W1t, b1, h1, psum1, psumsq1,
                  Hc, 2 * F, (blk >> 3) * 64, (blk & 7) * 64, As, Bs, sS, sSS);
    }
    grid_barrier(&ctr[1], MEGA_BLOCKS);

    // ---- P2: bn1 apply -> bf16 ----
    {
        const int i = (blk * 256 + t) * 4;
        float4 x = *reinterpret_cast<const float4*>(&h1[i]);
        const int c = i & 511;
        float xv[4] = {x.x, x.y, x.z, x.w};
        unsigned short ov[4];
#pragma unroll
        for (int j = 0; j < 4; ++j) {
            const int col = c + j;
            const float m = psum1[col] * invM;
            const float var = fmaxf(psumsq1[col] * invM - m * m, 0.f);
            const float rs = rsqrtf(var + 1e-5f);
            float h = fmaxf(g1[col] * (xv[j] - m) * rs + beta1[col], 0.f);
            ov[j] = f2bf(h);
        }
        ushort4 o4; o4.x = ov[0]; o4.y = ov[1]; o4.z = ov[2]; o4.w = ov[3];
        *reinterpret_cast<ushort4*>(&h1b[i]) = o4;
    }
    grid_barrier(&ctr[2], MEGA_BLOCKS);

    // ---- P3: gemm2 (1024x512x512) on blocks 0..127 ----
    if (blk < 128) {
        gemm_unit(h1b, W2t, b2, h2, psum2, psumsq2,
                  Hc, Hc, (blk >> 3) * 64, (blk & 7) * 64, As, Bs, sS, sSS);
    }
    grid_barrier(&ctr[3], MEGA_BLOCKS);

    // ---- P4: bn2 + head -> w, rows blk and blk+512 ----
    for (int half = 0; half < 2; ++half) {
        const int r = blk + half * 512;
        float a0 = 0.f, a1 = 0.f, a2 = 0.f;
        for (int c = t; c < Hc; c += 256) {
            const float m = psum2[c] * invM;
            const float var = fmaxf(psumsq2[c] * invM - m * m, 0.f);
            const float rs = rsqrtf(var + 1e-5f);
            float x = h2[(size_t)r * Hc + c];
            float h = fmaxf(g2[c] * (x - m) * rs + beta2[c], 0.f);
            a0 += h * W3[c * 3 + 0];
            a1 += h * W3[c * 3 + 1];
            a2 += h * W3[c * 3 + 2];
        }
#pragma unroll
        for (int off = 32; off >= 1; off >>= 1) {
            a0 += __shfl_down(a0, off, 64);
            a1 += __shfl_down(a1, off, 64);
            a2 += __shfl_down(a2, off, 64);
        }
        if ((t & 63) == 0) {
            redh[t >> 6][0] = a0; redh[t >> 6][1] = a1; redh[t >> 6][2] = a2;
        }
        __syncthreads();
        if (t == 0) {
            float s0 = redh[0][0] + redh[1][0] + redh[2][0] + redh[3][0];
            float s1 = redh[0][1] + redh[1][1] + redh[2][1] + redh[3][1];
            float s2 = redh[0][2] + redh[1][2] + redh[2][2] + redh[3][2];
            out_w[r * 3 + 0] = s0 + b3[0];
            out_w[r * 3 + 1] = s1 + b3[1];
            out_w[r * 3 + 2] = s2 + b3[2];
        }
        __syncthreads();
    }
    grid_barrier(&ctr[4], MEGA_BLOCKS);

    // ---- P5: RBF interpolation, chunk = blk ----
    {
        const int b = blk >> 6;
        const int chunk = blk & 63;
        if (t < 128) {
            const int base = (b * 128 + t) * 3;
            scx[t] = cp[base + 0]; scy[t] = cp[base + 1]; scz[t] = cp[base + 2];
            swx[t] = out_w[base + 0]; swy[t] = out_w[base + 1]; swz[t] = out_w[base + 2];
        }
        __syncthreads();

        const int n = chunk * 256 + t;
        const size_t pbase = ((size_t)b * N + n) * 3;
        const float x = src[pbase + 0], y = src[pbase + 1], z = src[pbase + 2];

        float mind = __builtin_huge_valf();
        for (int k = 0; k < 128; ++k) {
            float dx = x - scx[k], dy = y - scy[k], dz = z - scz[k];
            float d2 = dx * dx + dy * dy + dz * dz;
            mind = fminf(mind, d2);
        }
        float sum = 0.f, ax = 0.f, ay = 0.f, az = 0.f;
        for (int k = 0; k < 128; ++k) {
            float dx = x - scx[k], dy = y - scy[k], dz = z - scz[k];
            float d2 = dx * dx + dy * dy + dz * dz;
            float e = __expf(2.0f * (mind - d2));
            sum += e;
            ax += e * swx[k]; ay += e * swy[k]; az += e * swz[k];
        }
        const float inv = 1.0f / sum;
        ax *= inv; ay *= inv; az *= inv;
        delta[pbase + 0] = ax; delta[pbase + 1] = ay; delta[pbase + 2] = az;
        outp[pbase + 0] = x + ax; outp[pbase + 1] = y + ay; outp[pbase + 2] = z + az;
    }
}

// ---------------------------------------------------------------------------
// launch
// ---------------------------------------------------------------------------
extern "C" void kernel_launch(void* const* d_in, const int* in_sizes, int n_in,
                              void* d_out, int out_size, void* d_ws, size_t ws_size,
                              hipStream_t stream) {
    const int B = 8, N = 16384, M = 16384, F = 1024, H = 512, K = 128;

    const float* src       = (const float*)d_in[0];
    const float* ppf       = (const float*)d_in[1];
    const float* tgt       = (const float*)d_in[2];
    const float* tpf       = (const float*)d_in[3];
    const float* W1        = (const float*)d_in[4];
    const float* b1        = (const float*)d_in[5];
    const float* g1        = (const float*)d_in[6];
    const float* beta1     = (const float*)d_in[7];
    const float* W2        = (const float*)d_in[8];
    const float* b2        = (const float*)d_in[9];
    const float* g2        = (const float*)d_in[10];
    const float* beta2     = (const float*)d_in[11];
    const float* W3        = (const float*)d_in[12];
    const float* b3        = (const float*)d_in[13];

    float* out_output = (float*)d_out;                       // B*N*3
    float* out_delta  = out_output + (size_t)B * N * 3;      // B*N*3
    float* out_cp     = out_delta + (size_t)B * N * 3;       // B*K*3
    float* out_w      = out_cp + (size_t)B * K * 3;          // B*K*3

    char* ws = (char*)d_ws;
    int*            cp_idx = (int*)(ws + 0);                 // 4 KB
    float*          stats  = (float*)(ws + 4096);            // 2048 floats
    int*            ctr    = (int*)(ws + 12288);             // 8 ints
    unsigned short* mlp_b  = (unsigned short*)(ws + 16384);       // 4 MB
    unsigned short* W1t    = (unsigned short*)(ws + 4210688);     // 2 MB
    unsigned short* W2t    = (unsigned short*)(ws + 6307840);     // 512 KB
    float*          h1     = (float*)(ws + 6832128);              // 2 MB
    unsigned short* h1b    = (unsigned short*)(ws + 8929280);     // 1 MB
    float*          h2     = (float*)(ws + 9977856);              // 2 MB

    // 1. FPS + weight convert/transpose + stats/counter zero
    fps_conv_kernel<<<8 + CONV_BLOCKS, FPS_THREADS, 0, stream>>>(
        src, cp_idx, out_cp, W1, W2, W1t, W2t, stats, ctr, N, K);
    // 2. everything else in one persistent kernel with device barriers
    mega_kernel<<<MEGA_BLOCKS, 256, 0, stream>>>(
        src, tgt, out_cp, cp_idx, ppf, tpf, mlp_b, W1t, W2t,
        b1, g1, beta1, b2, g2, beta2, W3, b3,
        h1, h1b, h2, stats, ctr, out_w, out_output, out_delta,
        N, M, F, H);
}

// Round 8
// 316.258 us; speedup vs baseline: 2.2522x; 2.2522x over previous
//
#include <hip/hip_runtime.h>
#include <hip/hip_bf16.h>

#define FPS_THREADS 1024
#define FPS_PAIRS 8          // 8 float2 = 16 points per thread (16384/1024)
#define CONV_BLOCKS 120

typedef __attribute__((ext_vector_type(8))) short bf16x8;
typedef __attribute__((ext_vector_type(4))) float f32x4;
typedef __attribute__((ext_vector_type(2))) float f32x2;

// ---------------------------------------------------------------------------
// helpers
// ---------------------------------------------------------------------------
__device__ inline unsigned long long shfl_down_u64(unsigned long long x, int off) {
    unsigned int lo = (unsigned int)(x & 0xFFFFFFFFull);
    unsigned int hi = (unsigned int)(x >> 32);
    lo = __shfl_down(lo, off, 64);
    hi = __shfl_down(hi, off, 64);
    return (((unsigned long long)hi) << 32) | lo;
}

__device__ inline unsigned short f2bf(float x) {
    union { float f; unsigned int u; } v; v.f = x;
    unsigned int r = v.u + 0x7FFFu + ((v.u >> 16) & 1u);   // round-to-nearest-even
    return (unsigned short)(r >> 16);
}

// rocPRIM-style 64-lane max via DPP: row_shr 1/2/4/8 + row_bcast 15/31.
__device__ inline float wave_max_dpp(float v) {
    int w = __float_as_int(v);
#define DPP_MAX_STEP(ctrl, rmask)                                             \
    {                                                                         \
        int _t = __builtin_amdgcn_update_dpp(w, w, ctrl, rmask, 0xf, false);  \
        w = __float_as_int(fmaxf(__int_as_float(w), __int_as_float(_t)));     \
    }
    DPP_MAX_STEP(0x111, 0xf)   // row_shr:1
    DPP_MAX_STEP(0x112, 0xf)   // row_shr:2
    DPP_MAX_STEP(0x114, 0xf)   // row_shr:4
    DPP_MAX_STEP(0x118, 0xf)   // row_shr:8
    DPP_MAX_STEP(0x142, 0xa)   // row_bcast:15
    DPP_MAX_STEP(0x143, 0xc)   // row_bcast:31
#undef DPP_MAX_STEP
    return __int_as_float(__builtin_amdgcn_readlane(w, 63));
}

// ---------------------------------------------------------------------------
// 1. FPS (blocks 0..7, one per batch) + weight transpose/convert + stats zero
//    (blocks 8..127, runs in the shadow of the serial FPS).
//    dmin update on f32x2 (v_pk_* dual-FP32); argmax scan ascending j with
//    strict > (first max = smallest index, matching numpy). Wave max via DPP;
//    winning lanes publish packed (value || ~j) via one LDS atomicMax
//    (order-independent, tie -> smaller j). 3-slot rotating cell = race-free
//    reset. [R7 lesson: NO grid-spin-barrier mega-fusion — 512-block
//    agent-scope spin cost ~540us on 8 non-coherent XCD L2s.]
// ---------------------------------------------------------------------------
__global__ __launch_bounds__(FPS_THREADS) void fps_conv_kernel(
        const float* __restrict__ src, int* __restrict__ cp_idx,
        float* __restrict__ out_cp,
        const float* __restrict__ W1, const float* __restrict__ W2,
        unsigned short* __restrict__ W1t, unsigned short* __restrict__ W2t,
        float* __restrict__ stats, int N, int K) {
    const int t = threadIdx.x;
    if (blockIdx.x >= 8) {
        const int cb = blockIdx.x - 8;
        if (cb == 0) { stats[t] = 0.f; stats[t + 1024] = 0.f; }  // 2048 floats
        // W1t[n][k] = bf16(W1[k][n]);  W1: (2048, 512)
        for (size_t idx = (size_t)cb * 1024 + t; idx < (size_t)2048 * 512;
             idx += (size_t)CONV_BLOCKS * 1024) {
            int k = (int)(idx >> 9), n = (int)(idx & 511);
            W1t[(size_t)n * 2048 + k] = f2bf(W1[idx]);
        }
        // W2t[n][k] = bf16(W2[k][n]);  W2: (512, 512)
        for (size_t idx = (size_t)cb * 1024 + t; idx < (size_t)512 * 512;
             idx += (size_t)CONV_BLOCKS * 1024) {
            int k = (int)(idx >> 9), n = (int)(idx & 511);
            W2t[(size_t)n * 512 + k] = f2bf(W2[idx]);
        }
        return;
    }

    const int b = blockIdx.x;
    const float* p = src + (size_t)b * N * 3;

    f32x2 px2[FPS_PAIRS], py2[FPS_PAIRS], pz2[FPS_PAIRS], dm2[FPS_PAIRS];
#pragma unroll
    for (int a = 0; a < FPS_PAIRS; ++a) {
        int j0 = (2 * a) * FPS_THREADS + t;
        int j1 = (2 * a + 1) * FPS_THREADS + t;
        px2[a] = (f32x2){p[j0 * 3 + 0], p[j1 * 3 + 0]};
        py2[a] = (f32x2){p[j0 * 3 + 1], p[j1 * 3 + 1]};
        pz2[a] = (f32x2){p[j0 * 3 + 2], p[j1 * 3 + 2]};
        dm2[a] = (f32x2){__builtin_huge_valf(), __builtin_huge_valf()};
    }

    __shared__ unsigned long long slot[3];
    if (t == 0) { slot[0] = 0ull; slot[1] = 0ull; slot[2] = 0ull; }
    __syncthreads();

    int far = 0;
    int cur = 0;
    for (int k = 0;; ++k) {
        const float cx = p[far * 3 + 0];
        const float cy = p[far * 3 + 1];
        const float cz = p[far * 3 + 2];
        if (t == 0) {
            cp_idx[b * K + k] = far;
            out_cp[(b * K + k) * 3 + 0] = cx;
            out_cp[(b * K + k) * 3 + 1] = cy;
            out_cp[(b * K + k) * 3 + 2] = cz;
        }
        if (k == K - 1) break;

        const f32x2 vcx = (f32x2){cx, cx};
        const f32x2 vcy = (f32x2){cy, cy};
        const f32x2 vcz = (f32x2){cz, cz};

        // pass 1: packed dmin update (v_pk_add/v_pk_mul/v_pk_fma)
#pragma unroll
        for (int a = 0; a < FPS_PAIRS; ++a) {
            f32x2 dx = px2[a] - vcx;
            f32x2 dy = py2[a] - vcy;
            f32x2 dz = pz2[a] - vcz;
            f32x2 d = dx * dx;
            d += dy * dy;
            d += dz * dz;
            f32x2 dm = dm2[a];
            dm.x = fminf(dm.x, d.x);
            dm.y = fminf(dm.y, d.y);
            dm2[a] = dm;
        }
        // pass 2: per-thread argmax, ascending j, strict > (first max wins)
        float tmax = -1.0f;
        int jbest = 0;
#pragma unroll
        for (int a = 0; a < FPS_PAIRS; ++a) {
            f32x2 dm = dm2[a];
            bool c0 = dm.x > tmax;
            tmax = c0 ? dm.x : tmax;
            jbest = c0 ? ((2 * a) * FPS_THREADS + t) : jbest;
            bool c1 = dm.y > tmax;
            tmax = c1 ? dm.y : tmax;
            jbest = c1 ? ((2 * a + 1) * FPS_THREADS + t) : jbest;
        }

        const float wmax = wave_max_dpp(tmax);
        if (tmax == wmax) {
            unsigned long long pk =
                (((unsigned long long)__float_as_uint(wmax)) << 32) |
                (unsigned long long)(0xFFFFFFFFu - (unsigned int)jbest);
            atomicMax(&slot[cur], pk);
        }
        const int nxt = (cur == 2) ? 0 : cur + 1;
        if (t == 0) slot[nxt] = 0ull;
        __syncthreads();
        unsigned long long bb = slot[cur];
        far = (int)(0xFFFFFFFFu - (unsigned int)(bb & 0xFFFFFFFFull));
        cur = nxt;
    }
}

// ---------------------------------------------------------------------------
// 2. Fused: nearest target per control point + gather MLP input row (bf16).
// ---------------------------------------------------------------------------
__global__ __launch_bounds__(256) void nn_gather(
        const float* __restrict__ tgt, const float* __restrict__ cp,
        const int* __restrict__ cp_idx,
        const float* __restrict__ src_feats, const float* __restrict__ tgt_feats,
        unsigned short* __restrict__ mlp_b, int N, int M, int F) {
    const int bk = blockIdx.x;          // b*K + k
    const int b = bk >> 7;              // K = 128
    const int t = threadIdx.x;
    const float* tp = tgt + (size_t)b * M * 3;

    const float cx = cp[bk * 3 + 0], cy = cp[bk * 3 + 1], cz = cp[bk * 3 + 2];
    const float cp2 = cx * cx + cy * cy + cz * cz;

    unsigned long long best = ~0ull;
#pragma unroll 4
    for (int m = t; m < M; m += 256) {
        float tx = tp[m * 3 + 0], ty = tp[m * 3 + 1], tz = tp[m * 3 + 2];
        float tg2 = tx * tx + ty * ty + tz * tz;
        float cross = cx * tx + cy * ty + cz * tz;
        float v = (cp2 + tg2) - 2.0f * cross;
        unsigned int fb = __float_as_uint(v);
        fb = (fb & 0x80000000u) ? ~fb : (fb | 0x80000000u); // order-preserving flip
        unsigned long long pk = (((unsigned long long)fb) << 32) | (unsigned int)m;
        best = (pk < best) ? pk : best;   // min value, tie -> smaller m
    }
#pragma unroll
    for (int off = 32; off >= 1; off >>= 1) {
        unsigned long long o = shfl_down_u64(best, off);
        best = (o < best) ? o : best;
    }
    __shared__ unsigned long long red[4];
    __shared__ int snn;
    if ((t & 63) == 0) red[t >> 6] = best;
    __syncthreads();
    if (t == 0) {
        unsigned long long bb = red[0];
        for (int wv = 1; wv < 4; ++wv) bb = (red[wv] < bb) ? red[wv] : bb;
        snn = (int)(bb & 0xFFFFFFFFull);
    }
    __syncthreads();
    const int nn = snn;

    const float4* a = reinterpret_cast<const float4*>(
        src_feats + ((size_t)b * N + cp_idx[bk]) * F);
    const float4* c = reinterpret_cast<const float4*>(
        tgt_feats + ((size_t)b * M + nn) * F);
    unsigned short* o = mlp_b + (size_t)bk * 2 * F;
    float4 av = a[t];
    float4 cv = c[t];
    ushort4 a4, c4;
    a4.x = f2bf(av.x); a4.y = f2bf(av.y); a4.z = f2bf(av.z); a4.w = f2bf(av.w);
    c4.x = f2bf(cv.x); c4.y = f2bf(cv.y); c4.z = f2bf(cv.z); c4.w = f2bf(cv.w);
    *reinterpret_cast<ushort4*>(&o[t * 4]) = a4;            // cols [0,1024)
    *reinterpret_cast<ushort4*>(&o[F + t * 4]) = c4;        // cols [1024,2048)
}

// ---------------------------------------------------------------------------
// 3. bf16 MFMA GEMM + bias + fused column sum/sumsq stats.
//    C(MxN f32) = A(MxK bf16, row-major) @ Bt(NxK bf16, transposed) + bias.
//    64x64 tile, 256 threads (4 waves), mfma_f32_16x16x32_bf16.
// ---------------------------------------------------------------------------
__global__ __launch_bounds__(256) void gemm_mfma_stats(
        const unsigned short* __restrict__ A, const unsigned short* __restrict__ Bt,
        const float* __restrict__ bias, float* __restrict__ C,
        float* __restrict__ psum, float* __restrict__ psumsq,
        int M, int N, int K) {
    __shared__ __align__(16) unsigned short As[64][72];
    __shared__ __align__(16) unsigned short Bs[64][72];
    __shared__ float sS[64], sSS[64];
    const int tid = threadIdx.x;
    const int w = tid >> 6, l = tid & 63;
    const int m0 = blockIdx.y * 64, n0 = blockIdx.x * 64;

    f32x4 acc[4];
#pragma unroll
    for (int nt = 0; nt < 4; ++nt) acc[nt] = (f32x4){0.f, 0.f, 0.f, 0.f};

    const int lr = l & 15;        // row/col within 16-tile
    const int lg = l >> 4;        // k-group 0..3

    for (int kt = 0; kt < K; kt += 64) {
        __syncthreads();
#pragma unroll
        for (int s = 0; s < 2; ++s) {
            int u = tid + s * 256;
            int row = u >> 3, kc = (u & 7) * 8;
            *reinterpret_cast<uint4*>(&As[row][kc]) =
                *reinterpret_cast<const uint4*>(&A[(size_t)(m0 + row) * K + kt + kc]);
            *reinterpret_cast<uint4*>(&Bs[row][kc]) =
                *reinterpret_cast<const uint4*>(&Bt[(size_t)(n0 + row) * K + kt + kc]);
        }
        __syncthreads();
#pragma unroll
        for (int kf = 0; kf < 2; ++kf) {
            bf16x8 af = *reinterpret_cast<const bf16x8*>(&As[w * 16 + lr][kf * 32 + lg * 8]);
#pragma unroll
            for (int nt = 0; nt < 4; ++nt) {
                bf16x8 bfr = *reinterpret_cast<const bf16x8*>(&Bs[nt * 16 + lr][kf * 32 + lg * 8]);
                acc[nt] = __builtin_amdgcn_mfma_f32_16x16x32_bf16(af, bfr, acc[nt], 0, 0, 0);
            }
        }
    }

    // epilogue: bias add, C store, column stats
    if (tid < 64) { sS[tid] = 0.f; sSS[tid] = 0.f; }
    __syncthreads();
#pragma unroll
    for (int nt = 0; nt < 4; ++nt) {
        const int col = n0 + nt * 16 + lr;
        const float bv = bias[col];
        float s = 0.f, ss = 0.f;
#pragma unroll
        for (int r = 0; r < 4; ++r) {
            const int row = m0 + w * 16 + lg * 4 + r;     // C/D: row=(lane>>4)*4+reg
            float v = acc[nt][r] + bv;
            C[(size_t)row * N + col] = v;
            s += v; ss += v * v;
        }
        s += __shfl_xor(s, 16, 64); ss += __shfl_xor(ss, 16, 64);
        s += __shfl_xor(s, 32, 64); ss += __shfl_xor(ss, 32, 64);
        if (lg == 0) {                                     // lanes 0..15 of each wave
            atomicAdd(&sS[nt * 16 + lr], s);
            atomicAdd(&sSS[nt * 16 + lr], ss);
        }
    }
    __syncthreads();
    if (tid < 64) {
        atomicAdd(&psum[n0 + tid], sS[tid]);
        atomicAdd(&psumsq[n0 + tid], sSS[tid]);
    }
}

// ---------------------------------------------------------------------------
// 4. BN apply + ReLU: h1 (f32) -> h1b (bf16) for layer-2 GEMM
// ---------------------------------------------------------------------------
__global__ __launch_bounds__(256) void bn_apply_bf16(
        const float* __restrict__ Hm, const float* __restrict__ psum,
        const float* __restrict__ psumsq, const float* __restrict__ g,
        const float* __restrict__ beta, unsigned short* __restrict__ out,
        float invM) {
    const int i = (blockIdx.x * 256 + threadIdx.x) * 4;
    float4 x = *reinterpret_cast<const float4*>(&Hm[i]);
    const int c = i & 511;                 // H = 512
    ushort4 o4;
    float xv[4] = {x.x, x.y, x.z, x.w};
    unsigned short ov[4];
#pragma unroll
    for (int j = 0; j < 4; ++j) {
        const int col = c + j;
        const float m = psum[col] * invM;
        const float var = fmaxf(psumsq[col] * invM - m * m, 0.f);
        const float rs = rsqrtf(var + 1e-5f);
        float h = fmaxf(g[col] * (xv[j] - m) * rs + beta[col], 0.f);
        ov[j] = f2bf(h);
    }
    o4.x = ov[0]; o4.y = ov[1]; o4.z = ov[2]; o4.w = ov[3];
    *reinterpret_cast<ushort4*>(&out[i]) = o4;
}

// ---------------------------------------------------------------------------
// 5. Fused BN2 + head: w (1024x3) = relu(bn(h2)) @ W3 + b3 ; one block per row
// ---------------------------------------------------------------------------
__global__ __launch_bounds__(256) void bn_head(
        const float* __restrict__ H2, const float* __restrict__ psum,
        const float* __restrict__ psumsq, const float* __restrict__ g,
        const float* __restrict__ beta, const float* __restrict__ W3,
        const float* __restrict__ b3, float* __restrict__ w_out,
        int Ncols, float invM) {
    const int r = blockIdx.x;
    const int t = threadIdx.x;
    float a0 = 0.f, a1 = 0.f, a2 = 0.f;
    for (int c = t; c < Ncols; c += 256) {
        const float m = psum[c] * invM;
        const float var = fmaxf(psumsq[c] * invM - m * m, 0.f);
        const float rs = rsqrtf(var + 1e-5f);
        float x = H2[(size_t)r * Ncols + c];
        float h = fmaxf(g[c] * (x - m) * rs + beta[c], 0.f);
        a0 += h * W3[c * 3 + 0];
        a1 += h * W3[c * 3 + 1];
        a2 += h * W3[c * 3 + 2];
    }
#pragma unroll
    for (int off = 32; off >= 1; off >>= 1) {
        a0 += __shfl_down(a0, off, 64);
        a1 += __shfl_down(a1, off, 64);
        a2 += __shfl_down(a2, off, 64);
    }
    __shared__ float red[4][3];
    if ((t & 63) == 0) {
        red[t >> 6][0] = a0; red[t >> 6][1] = a1; red[t >> 6][2] = a2;
    }
    __syncthreads();
    if (t == 0) {
        float s0 = red[0][0] + red[1][0] + red[2][0] + red[3][0];
        float s1 = red[0][1] + red[1][1] + red[2][1] + red[3][1];
        float s2 = red[0][2] + red[1][2] + red[2][2] + red[3][2];
        w_out[r * 3 + 0] = s0 + b3[0];
        w_out[r * 3 + 1] = s1 + b3[1];
        w_out[r * 3 + 2] = s2 + b3[2];
    }
}

// ---------------------------------------------------------------------------
// 6. RBF softmax interpolation: output = src + (softmax(-2*d2) @ w)
// ---------------------------------------------------------------------------
__global__ __launch_bounds__(256) void rbf_kernel(
        const float* __restrict__ src, const float* __restrict__ cp,
        const float* __restrict__ w, float* __restrict__ outp,
        float* __restrict__ delta, int N, int K) {
    __shared__ float scx[128], scy[128], scz[128];
    __shared__ float swx[128], swy[128], swz[128];
    const int b = blockIdx.x >> 6;      // 64 chunks of 256 per batch
    const int chunk = blockIdx.x & 63;
    const int t = threadIdx.x;
    if (t < K) {
        const int base = (b * K + t) * 3;
        scx[t] = cp[base + 0]; scy[t] = cp[base + 1]; scz[t] = cp[base + 2];
        swx[t] = w[base + 0];  swy[t] = w[base + 1];  swz[t] = w[base + 2];
    }
    __syncthreads();

    const int n = chunk * 256 + t;
    const size_t pbase = ((size_t)b * N + n) * 3;
    const float x = src[pbase + 0], y = src[pbase + 1], z = src[pbase + 2];

    float mind = __builtin_huge_valf();
    for (int k = 0; k < K; ++k) {
        float dx = x - scx[k], dy = y - scy[k], dz = z - scz[k];
        float d2 = dx * dx + dy * dy + dz * dz;
        mind = fminf(mind, d2);
    }
    float sum = 0.f, ax = 0.f, ay = 0.f, az = 0.f;
    for (int k = 0; k < K; ++k) {
        float dx = x - scx[k], dy = y - scy[k], dz = z - scz[k];
        float d2 = dx * dx + dy * dy + dz * dz;
        float e = __expf(2.0f * (mind - d2));   // softmax(-2*d2), max-subtracted
        sum += e;
        ax += e * swx[k]; ay += e * swy[k]; az += e * swz[k];
    }
    const float inv = 1.0f / sum;
    ax *= inv; ay *= inv; az *= inv;
    delta[pbase + 0] = ax; delta[pbase + 1] = ay; delta[pbase + 2] = az;
    outp[pbase + 0] = x + ax; outp[pbase + 1] = y + ay; outp[pbase + 2] = z + az;
}

// ---------------------------------------------------------------------------
// launch
// ---------------------------------------------------------------------------
extern "C" void kernel_launch(void* const* d_in, const int* in_sizes, int n_in,
                              void* d_out, int out_size, void* d_ws, size_t ws_size,
                              hipStream_t stream) {
    const int B = 8, N = 16384, M = 16384, F = 1024, H = 512, K = 128;
    const int BK = B * K;               // 1024 MLP rows

    const float* src       = (const float*)d_in[0];
    const float* ppf       = (const float*)d_in[1];
    const float* tgt       = (const float*)d_in[2];
    const float* tpf       = (const float*)d_in[3];
    const float* W1        = (const float*)d_in[4];
    const float* b1        = (const float*)d_in[5];
    const float* g1        = (const float*)d_in[6];
    const float* beta1     = (const float*)d_in[7];
    const float* W2        = (const float*)d_in[8];
    const float* b2        = (const float*)d_in[9];
    const float* g2        = (const float*)d_in[10];
    const float* beta2     = (const float*)d_in[11];
    const float* W3        = (const float*)d_in[12];
    const float* b3        = (const float*)d_in[13];

    float* out_output = (float*)d_out;                       // B*N*3
    float* out_delta  = out_output + (size_t)B * N * 3;      // B*N*3
    float* out_cp     = out_delta + (size_t)B * N * 3;       // B*K*3
    float* out_w      = out_cp + (size_t)B * K * 3;          // B*K*3

    char* ws = (char*)d_ws;
    int*            cp_idx = (int*)(ws + 0);                 // 4 KB
    float*          stats  = (float*)(ws + 4096);            // 2048 floats (8 KB)
    float* psum1   = stats;
    float* psumsq1 = stats + 512;
    float* psum2   = stats + 1024;
    float* psumsq2 = stats + 1536;
    unsigned short* mlp_b  = (unsigned short*)(ws + 16384);       // 1024x2048 bf16 (4 MB)
    unsigned short* W1t    = (unsigned short*)(ws + 4210688);     // 512x2048 bf16 (2 MB)
    unsigned short* W2t    = (unsigned short*)(ws + 6307840);     // 512x512 bf16 (512 KB)
    float*          h1     = (float*)(ws + 6832128);              // 1024x512 f32 (2 MB)
    unsigned short* h1b    = (unsigned short*)(ws + 8929280);     // 1024x512 bf16 (1 MB)
    float*          h2     = (float*)(ws + 9977856);              // 1024x512 f32 (2 MB)

    // 1. FPS + weight convert/transpose + stats zero
    fps_conv_kernel<<<8 + CONV_BLOCKS, FPS_THREADS, 0, stream>>>(
        src, cp_idx, out_cp, W1, W2, W1t, W2t, stats, N, K);
    // 2. fused nearest-target + gather (bf16)
    nn_gather<<<BK, 256, 0, stream>>>(tgt, out_cp, cp_idx, ppf, tpf, mlp_b, N, M, F);
    // 3. layer 1: MFMA GEMM + bias + stats
    gemm_mfma_stats<<<dim3(H / 64, BK / 64), 256, 0, stream>>>(
        mlp_b, W1t, b1, h1, psum1, psumsq1, BK, H, 2 * F);
    // 4. BN1 apply -> bf16
    bn_apply_bf16<<<(BK * H / 4) / 256, 256, 0, stream>>>(
        h1, psum1, psumsq1, g1, beta1, h1b, 1.0f / BK);
    // 5. layer 2: MFMA GEMM + bias + stats
    gemm_mfma_stats<<<dim3(H / 64, BK / 64), 256, 0, stream>>>(
        h1b, W2t, b2, h2, psum2, psumsq2, BK, H, H);
    // 6. fused BN2 + head -> w
    bn_head<<<BK, 256, 0, stream>>>(
        h2, psum2, psumsq2, g2, beta2, W3, b3, out_w, H, 1.0f / BK);
    // 7. RBF interpolation -> output, delta
    rbf_kernel<<<B * (N / 256), 256, 0, stream>>>(src, out_cp, out_w, out_output, out_delta, N, K);
}